// Round 9
// baseline (279.607 us; speedup 1.0000x reference)
//
#include <hip/hip_runtime.h>
#include <cstddef>
#include <cmath>

#define NB  4096
#define TT  200
#define DD  64
#define NH1 80
#define NH2 40

typedef _Float16 half8 __attribute__((ext_vector_type(8)));
typedef float    f32x4 __attribute__((ext_vector_type(4)));

// ---- workspace layout (bytes) ----
// wQh [4096][80] f32 : q@(W1a+W1c) + b1
// wF1 : layer-1 B fragments, lane-major: [(n*4+s)*64 + lane] -> half8  (20480 B)
// wF2 : layer-2 B fragments, lane-major: [(n*3+s)*64 + lane] -> half8  (9216 B)
static const size_t OFF_QH = 0;
static const size_t OFF_F1 = (size_t)NB * NH1 * 4;
static const size_t OFF_F2 = OFF_F1 + (size_t)5 * 4 * 64 * 8 * 2;

__global__ void prep_weights(const float* __restrict__ W1, const float* __restrict__ W2,
                             _Float16* __restrict__ wF1, _Float16* __restrict__ wF2)
{
    const int tid = blockIdx.x * blockDim.x + threadIdx.x;
    const int stride = blockDim.x * gridDim.x;
    // layer-1 fragments: value = B[kk][h], h = n*16+(l&15), kk = s*32+(l>>4)*8+j
    for (int i = tid; i < 5 * 4 * 64 * 8; i += stride) {
        const int j = i & 7, l = (i >> 3) & 63, s = (i >> 9) & 3, n = i >> 11;
        const int h  = n * 16 + (l & 15);
        const int kk = s * 32 + (l >> 4) * 8 + j;
        const float w = (kk < 64) ? (W1[(64 + kk) * NH1 + h] - W1[(128 + kk) * NH1 + h])
                                  :  W1[(128 + kk) * NH1 + h];
        wF1[i] = (_Float16)w;
    }
    // layer-2 fragments: value = W2[kk][n2], n2 = n*16+(l&15), kk = s*32+(l>>4)*8+j
    for (int i = tid; i < 3 * 3 * 64 * 8; i += stride) {
        const int j = i & 7, l = (i >> 3) & 63;
        const int s = (i >> 9) % 3, n = i / 1536;
        const int kk = s * 32 + (l >> 4) * 8 + j;
        const int n2 = n * 16 + (l & 15);
        const float w = (kk < NH1 && n2 < NH2) ? W2[kk * NH2 + n2] : 0.f;
        wF2[i] = (_Float16)w;
    }
}

__global__ void prep_qh(const float* __restrict__ q, const float* __restrict__ W1,
                        const float* __restrict__ b1, float* __restrict__ wQh)
{
    const int idx = blockIdx.x * blockDim.x + threadIdx.x;
    if (idx >= NB * NH1) return;
    const int b = idx / NH1;
    const int h = idx - b * NH1;
    const float* qb = q + (size_t)b * DD;
    float acc = b1[h];
#pragma unroll 8
    for (int d = 0; d < DD; ++d)
        acc += qb[d] * (W1[d * NH1 + h] + W1[(128 + d) * NH1 + h]);
    wQh[idx] = acc;
}

// one wave per b; group-split online softmax; TWO tile-chains in flight (ILP-2);
// weights in LDS to keep arch-VGPR demand inside the (256,2) budget
__global__ __launch_bounds__(256, 2)
void attn_main(const float* __restrict__ q, const float* __restrict__ k,
               const float* __restrict__ v, const int* __restrict__ mask,
               const float* __restrict__ Wf, const float* __restrict__ b2g,
               const float* __restrict__ bf,
               const float* __restrict__ wQh, const _Float16* __restrict__ wF1,
               const _Float16* __restrict__ wF2, float* __restrict__ out)
{
    __shared__ __align__(16) _Float16 sWF1[5 * 4 * 64 * 8];   // 20480 B
    __shared__ __align__(16) _Float16 sWF2[3 * 3 * 64 * 8];   //  9216 B
    __shared__ __align__(16) char sH1[4 * 2 * 3072];          // per-wave A/B h1 (24576 B)
    __shared__ __align__(16) float sBias[4][208];             //  3328 B

    const int tid  = threadIdx.x;
    const int wid  = tid >> 6;
    const int lane = tid & 63;
    const int lr   = lane & 15;
    const int lg   = lane >> 4;
    const int b    = blockIdx.x * 4 + wid;      // each wave owns one batch row
    const int d0   = lr * 4;                    // this lane's v/out column slice
    const float bfv = bf[0];

    // stage weight fragments into LDS (block-shared)
    {
        f32x4* dst1 = (f32x4*)sWF1;
        const f32x4* src1 = (const f32x4*)wF1;
        for (int i = tid; i < 1280; i += 256) dst1[i] = src1[i];
        f32x4* dst2 = (f32x4*)sWF2;
        const f32x4* src2 = (const f32x4*)wF2;
        for (int i = tid; i < 576; i += 256) dst2[i] = src2[i];
    }

    // per-wave mask bias: +big = keep, CONST_MIN = masked, -inf = pad rows (t>=200)
    for (int i = lane; i < 208; i += 64) {
        float bv;
        if (i < TT) bv = mask[(size_t)b * TT + i] ? 3.0e38f : -4294967295.0f;
        else        bv = -INFINITY;
        sBias[wid][i] = bv;
    }

    // per-lane slices of qh / Wf / b2
    float qhr[5];
#pragma unroll
    for (int n = 0; n < 5; ++n) qhr[n] = wQh[(size_t)b * NH1 + n * 16 + lr];
    float wfr[3], bbr[3];
#pragma unroll
    for (int n = 0; n < 3; ++n) {
        const int hc = n * 16 + lr;
        wfr[n] = (hc < NH2) ? Wf[hc]  : 0.f;
        bbr[n] = (hc < NH2) ? b2g[hc] : 0.f;
    }

    // q in packed fp16
    half8 qh0, qh1;
    {
        const float* qb = q + (size_t)b * DD;
#pragma unroll
        for (int j = 0; j < 8; ++j) qh0[j] = (_Float16)qb[lg * 8 + j];
#pragma unroll
        for (int j = 0; j < 8; ++j) qh1[j] = (_Float16)qb[32 + lg * 8 + j];
    }

    // per-wave A/B h1 buffers; zero-pad cols 80..95 (slots 10,11), swizzled
    char* h1A = sH1 + wid * 6144;
    char* h1B = h1A + 3072;
    if (lane < 32) {
        const int row = lane >> 1;
        const int slotL = 10 + (lane & 1);
        const f32x4 z4 = {};
        *(f32x4*)(h1A + row * 192 + ((slotL ^ (row & 3)) << 4)) = z4;
        *(f32x4*)(h1B + row * 192 + ((slotL ^ (row & 3)) << 4)) = z4;
    }

    __syncthreads();   // sWF1 / sWF2 ready

    const half8* sF1v = (const half8*)sWF1;
    const half8* sF2v = (const half8*)sWF2;
    const float* vb   = v + (size_t)b * (TT * DD);
    const float* kb   = k + (size_t)b * (TT * DD);

    // per-GROUP online softmax state (rows = this group's 4 rows per tile)
    float m = -INFINITY, s = 0.f;
    f32x4 acc = {};

    // prologue: k tiles 0 and 1 into registers
    f32x4 kA0, kA1, kA2, kA3, kB0, kB1, kB2, kB3;
    {
        const float* krA = kb + (size_t)lr * DD;
        kA0 = *(const f32x4*)(krA + lg * 8);
        kA1 = *(const f32x4*)(krA + lg * 8 + 4);
        kA2 = *(const f32x4*)(krA + 32 + lg * 8);
        kA3 = *(const f32x4*)(krA + 32 + lg * 8 + 4);
        const float* krB = kb + (size_t)(16 + lr) * DD;
        kB0 = *(const f32x4*)(krB + lg * 8);
        kB1 = *(const f32x4*)(krB + lg * 8 + 4);
        kB2 = *(const f32x4*)(krB + 32 + lg * 8);
        kB3 = *(const f32x4*)(krB + 32 + lg * 8 + 4);
    }

    for (int pair = 0; pair < 6; ++pair) {
        const int mtA = pair * 2, mtB = pair * 2 + 1;

        // ---- v loads for both tiles (rows < 200 for all pairs; no clamp needed) ----
        const int trA = mtA * 16 + lg * 4;
        const int trB = mtB * 16 + lg * 4;
        const f32x4 vA0 = *(const f32x4*)(vb + (size_t)(trA + 0) * DD + d0);
        const f32x4 vA1 = *(const f32x4*)(vb + (size_t)(trA + 1) * DD + d0);
        const f32x4 vA2 = *(const f32x4*)(vb + (size_t)(trA + 2) * DD + d0);
        const f32x4 vA3 = *(const f32x4*)(vb + (size_t)(trA + 3) * DD + d0);
        const f32x4 vB0 = *(const f32x4*)(vb + (size_t)(trB + 0) * DD + d0);
        const f32x4 vB1 = *(const f32x4*)(vb + (size_t)(trB + 1) * DD + d0);
        const f32x4 vB2 = *(const f32x4*)(vb + (size_t)(trB + 2) * DD + d0);
        const f32x4 vB3 = *(const f32x4*)(vb + (size_t)(trB + 3) * DD + d0);

        // ---- convert both k tiles to fp16 A-fragments ----
        half8 afA0, afA1, afB0, afB1;
#pragma unroll
        for (int j = 0; j < 4; ++j) {
            afA0[j] = (_Float16)kA0[j];  afA0[j + 4] = (_Float16)kA1[j];
            afA1[j] = (_Float16)kA2[j];  afA1[j + 4] = (_Float16)kA3[j];
            afB0[j] = (_Float16)kB0[j];  afB0[j + 4] = (_Float16)kB1[j];
            afB1[j] = (_Float16)kB2[j];  afB1[j + 4] = (_Float16)kB3[j];
        }
        const half8 afA2 = qh0 * afA0;
        const half8 afA3 = qh1 * afA1;
        const half8 afB2 = qh0 * afB0;
        const half8 afB3 = qh1 * afB1;

        // ---- prefetch next pair's k tiles (tile 12 rows need clamp; skip tile 13) ----
        {
            const int tA = min((pair * 2 + 2) * 16 + lr, TT - 1);
            const float* krA = kb + (size_t)tA * DD;
            kA0 = *(const f32x4*)(krA + lg * 8);
            kA1 = *(const f32x4*)(krA + lg * 8 + 4);
            kA2 = *(const f32x4*)(krA + 32 + lg * 8);
            kA3 = *(const f32x4*)(krA + 32 + lg * 8 + 4);
            if (pair < 5) {
                const float* krB = kb + (size_t)((pair * 2 + 3) * 16 + lr) * DD;
                kB0 = *(const f32x4*)(krB + lg * 8);
                kB1 = *(const f32x4*)(krB + lg * 8 + 4);
                kB2 = *(const f32x4*)(krB + 32 + lg * 8);
                kB3 = *(const f32x4*)(krB + 32 + lg * 8 + 4);
            }
        }

        // ---- layer 1 for A and B (independent chains) ----
#pragma unroll
        for (int n = 0; n < 5; ++n) {
            f32x4 a = { qhr[n], qhr[n], qhr[n], qhr[n] };
            a = __builtin_amdgcn_mfma_f32_16x16x32_f16(afA0, sF1v[(n * 4 + 0) * 64 + lane], a, 0, 0, 0);
            a = __builtin_amdgcn_mfma_f32_16x16x32_f16(afA1, sF1v[(n * 4 + 1) * 64 + lane], a, 0, 0, 0);
            a = __builtin_amdgcn_mfma_f32_16x16x32_f16(afA2, sF1v[(n * 4 + 2) * 64 + lane], a, 0, 0, 0);
            a = __builtin_amdgcn_mfma_f32_16x16x32_f16(afA3, sF1v[(n * 4 + 3) * 64 + lane], a, 0, 0, 0);
            f32x4 bacc = { qhr[n], qhr[n], qhr[n], qhr[n] };
            bacc = __builtin_amdgcn_mfma_f32_16x16x32_f16(afB0, sF1v[(n * 4 + 0) * 64 + lane], bacc, 0, 0, 0);
            bacc = __builtin_amdgcn_mfma_f32_16x16x32_f16(afB1, sF1v[(n * 4 + 1) * 64 + lane], bacc, 0, 0, 0);
            bacc = __builtin_amdgcn_mfma_f32_16x16x32_f16(afB2, sF1v[(n * 4 + 2) * 64 + lane], bacc, 0, 0, 0);
            bacc = __builtin_amdgcn_mfma_f32_16x16x32_f16(afB3, sF1v[(n * 4 + 3) * 64 + lane], bacc, 0, 0, 0);
            const int slot   = (n * 16 + lr) >> 3;
            const int within = ((n * 16 + lr) & 7) * 2;
#pragma unroll
            for (int j = 0; j < 4; ++j) {
                const int r = lg * 4 + j;
                const int off = r * 192 + ((slot ^ (r & 3)) << 4) + within;
                *(_Float16*)(h1A + off) = (_Float16)fmaxf(a[j], 0.f);
                *(_Float16*)(h1B + off) = (_Float16)fmaxf(bacc[j], 0.f);
            }
        }

        // ---- layer 2 for A and B ----
        half8 aA0 = *(const half8*)(h1A + lr * 192 + (((0 + lg) ^ (lr & 3)) << 4));
        half8 aA1 = *(const half8*)(h1A + lr * 192 + (((4 + lg) ^ (lr & 3)) << 4));
        half8 aA2 = *(const half8*)(h1A + lr * 192 + (((8 + lg) ^ (lr & 3)) << 4));
        half8 aB0 = *(const half8*)(h1B + lr * 192 + (((0 + lg) ^ (lr & 3)) << 4));
        half8 aB1 = *(const half8*)(h1B + lr * 192 + (((4 + lg) ^ (lr & 3)) << 4));
        half8 aB2 = *(const half8*)(h1B + lr * 192 + (((8 + lg) ^ (lr & 3)) << 4));

        float pA0 = 0.f, pA1 = 0.f, pA2 = 0.f, pA3 = 0.f;
        float pB0 = 0.f, pB1 = 0.f, pB2 = 0.f, pB3 = 0.f;
#pragma unroll
        for (int n = 0; n < 3; ++n) {
            f32x4 cA = { bbr[n], bbr[n], bbr[n], bbr[n] };
            cA = __builtin_amdgcn_mfma_f32_16x16x32_f16(aA0, sF2v[(n * 3 + 0) * 64 + lane], cA, 0, 0, 0);
            cA = __builtin_amdgcn_mfma_f32_16x16x32_f16(aA1, sF2v[(n * 3 + 1) * 64 + lane], cA, 0, 0, 0);
            cA = __builtin_amdgcn_mfma_f32_16x16x32_f16(aA2, sF2v[(n * 3 + 2) * 64 + lane], cA, 0, 0, 0);
            f32x4 cB = { bbr[n], bbr[n], bbr[n], bbr[n] };
            cB = __builtin_amdgcn_mfma_f32_16x16x32_f16(aB0, sF2v[(n * 3 + 0) * 64 + lane], cB, 0, 0, 0);
            cB = __builtin_amdgcn_mfma_f32_16x16x32_f16(aB1, sF2v[(n * 3 + 1) * 64 + lane], cB, 0, 0, 0);
            cB = __builtin_amdgcn_mfma_f32_16x16x32_f16(aB2, sF2v[(n * 3 + 2) * 64 + lane], cB, 0, 0, 0);
            pA0 = fmaf(fmaxf(cA[0], 0.f), wfr[n], pA0);
            pA1 = fmaf(fmaxf(cA[1], 0.f), wfr[n], pA1);
            pA2 = fmaf(fmaxf(cA[2], 0.f), wfr[n], pA2);
            pA3 = fmaf(fmaxf(cA[3], 0.f), wfr[n], pA3);
            pB0 = fmaf(fmaxf(cB[0], 0.f), wfr[n], pB0);
            pB1 = fmaf(fmaxf(cB[1], 0.f), wfr[n], pB1);
            pB2 = fmaf(fmaxf(cB[2], 0.f), wfr[n], pB2);
            pB3 = fmaf(fmaxf(cB[3], 0.f), wfr[n], pB3);
        }

        // ---- butterflies of both tiles interleaved (latency overlap) ----
#pragma unroll
        for (int off = 1; off < 16; off <<= 1) {
            pA0 += __shfl_xor(pA0, off);
            pB0 += __shfl_xor(pB0, off);
            pA1 += __shfl_xor(pA1, off);
            pB1 += __shfl_xor(pB1, off);
            pA2 += __shfl_xor(pA2, off);
            pB2 += __shfl_xor(pB2, off);
            pA3 += __shfl_xor(pA3, off);
            pB3 += __shfl_xor(pB3, off);
        }

        // ---- group-private online masked softmax + v accumulation: A then B ----
        {
            const f32x4 b4 = *(const f32x4*)&sBias[wid][mtA * 16 + lg * 4];
            const float l0 = fminf(pA0, b4[0]) + bfv;
            const float l1 = fminf(pA1, b4[1]) + bfv;
            const float l2 = fminf(pA2, b4[2]) + bfv;
            const float l3 = fminf(pA3, b4[3]) + bfv;
            const float lmax = fmaxf(fmaxf(l0, l1), fmaxf(l2, l3));
            const float mnew = fmaxf(m, lmax);
            const float sc = __expf(m - mnew);
            const float w0 = __expf(l0 - mnew);
            const float w1 = __expf(l1 - mnew);
            const float w2 = __expf(l2 - mnew);
            const float w3 = __expf(l3 - mnew);
            s = s * sc + (w0 + w1 + w2 + w3);
            acc *= sc;
            acc += vA0 * w0; acc += vA1 * w1; acc += vA2 * w2; acc += vA3 * w3;
            m = mnew;
        }
        {
            const f32x4 b4 = *(const f32x4*)&sBias[wid][mtB * 16 + lg * 4];
            const float l0 = fminf(pB0, b4[0]) + bfv;
            const float l1 = fminf(pB1, b4[1]) + bfv;
            const float l2 = fminf(pB2, b4[2]) + bfv;
            const float l3 = fminf(pB3, b4[3]) + bfv;
            const float lmax = fmaxf(fmaxf(l0, l1), fmaxf(l2, l3));
            const float mnew = fmaxf(m, lmax);
            const float sc = __expf(m - mnew);
            const float w0 = __expf(l0 - mnew);
            const float w1 = __expf(l1 - mnew);
            const float w2 = __expf(l2 - mnew);
            const float w3 = __expf(l3 - mnew);
            s = s * sc + (w0 + w1 + w2 + w3);
            acc *= sc;
            acc += vB0 * w0; acc += vB1 * w1; acc += vB2 * w2; acc += vB3 * w3;
            m = mnew;
        }
    }

    // ---- epilogue: tile 12 (kA registers hold it; rows >=200 killed by -inf bias) ----
    {
        const int tr = 12 * 16 + lg * 4;   // 192..207
        const f32x4 vA0 = *(const f32x4*)(vb + (size_t)min(tr + 0, TT - 1) * DD + d0);
        const f32x4 vA1 = *(const f32x4*)(vb + (size_t)min(tr + 1, TT - 1) * DD + d0);
        const f32x4 vA2 = *(const f32x4*)(vb + (size_t)min(tr + 2, TT - 1) * DD + d0);
        const f32x4 vA3 = *(const f32x4*)(vb + (size_t)min(tr + 3, TT - 1) * DD + d0);

        half8 afA0, afA1;
#pragma unroll
        for (int j = 0; j < 4; ++j) {
            afA0[j] = (_Float16)kA0[j];  afA0[j + 4] = (_Float16)kA1[j];
            afA1[j] = (_Float16)kA2[j];  afA1[j + 4] = (_Float16)kA3[j];
        }
        const half8 afA2 = qh0 * afA0;
        const half8 afA3 = qh1 * afA1;

#pragma unroll
        for (int n = 0; n < 5; ++n) {
            f32x4 a = { qhr[n], qhr[n], qhr[n], qhr[n] };
            a = __builtin_amdgcn_mfma_f32_16x16x32_f16(afA0, sF1v[(n * 4 + 0) * 64 + lane], a, 0, 0, 0);
            a = __builtin_amdgcn_mfma_f32_16x16x32_f16(afA1, sF1v[(n * 4 + 1) * 64 + lane], a, 0, 0, 0);
            a = __builtin_amdgcn_mfma_f32_16x16x32_f16(afA2, sF1v[(n * 4 + 2) * 64 + lane], a, 0, 0, 0);
            a = __builtin_amdgcn_mfma_f32_16x16x32_f16(afA3, sF1v[(n * 4 + 3) * 64 + lane], a, 0, 0, 0);
            const int slot   = (n * 16 + lr) >> 3;
            const int within = ((n * 16 + lr) & 7) * 2;
#pragma unroll
            for (int j = 0; j < 4; ++j) {
                const int r = lg * 4 + j;
                *(_Float16*)(h1A + r * 192 + ((slot ^ (r & 3)) << 4) + within) = (_Float16)fmaxf(a[j], 0.f);
            }
        }

        half8 aA0 = *(const half8*)(h1A + lr * 192 + (((0 + lg) ^ (lr & 3)) << 4));
        half8 aA1 = *(const half8*)(h1A + lr * 192 + (((4 + lg) ^ (lr & 3)) << 4));
        half8 aA2 = *(const half8*)(h1A + lr * 192 + (((8 + lg) ^ (lr & 3)) << 4));

        float p0 = 0.f, p1 = 0.f, p2 = 0.f, p3 = 0.f;
#pragma unroll
        for (int n = 0; n < 3; ++n) {
            f32x4 c2 = { bbr[n], bbr[n], bbr[n], bbr[n] };
            c2 = __builtin_amdgcn_mfma_f32_16x16x32_f16(aA0, sF2v[(n * 3 + 0) * 64 + lane], c2, 0, 0, 0);
            c2 = __builtin_amdgcn_mfma_f32_16x16x32_f16(aA1, sF2v[(n * 3 + 1) * 64 + lane], c2, 0, 0, 0);
            c2 = __builtin_amdgcn_mfma_f32_16x16x32_f16(aA2, sF2v[(n * 3 + 2) * 64 + lane], c2, 0, 0, 0);
            p0 = fmaf(fmaxf(c2[0], 0.f), wfr[n], p0);
            p1 = fmaf(fmaxf(c2[1], 0.f), wfr[n], p1);
            p2 = fmaf(fmaxf(c2[2], 0.f), wfr[n], p2);
            p3 = fmaf(fmaxf(c2[3], 0.f), wfr[n], p3);
        }
#pragma unroll
        for (int off = 1; off < 16; off <<= 1) {
            p0 += __shfl_xor(p0, off);
            p1 += __shfl_xor(p1, off);
            p2 += __shfl_xor(p2, off);
            p3 += __shfl_xor(p3, off);
        }

        const f32x4 b4 = *(const f32x4*)&sBias[wid][12 * 16 + lg * 4];
        const float l0 = fminf(p0, b4[0]) + bfv;
        const float l1 = fminf(p1, b4[1]) + bfv;
        const float l2 = fminf(p2, b4[2]) + bfv;
        const float l3 = fminf(p3, b4[3]) + bfv;
        const float lmax = fmaxf(fmaxf(l0, l1), fmaxf(l2, l3));
        const float mnew = fmaxf(m, lmax);
        const float sc = __expf(m - mnew);
        const float w0 = __expf(l0 - mnew);
        const float w1 = __expf(l1 - mnew);
        const float w2 = __expf(l2 - mnew);
        const float w3 = __expf(l3 - mnew);
        s = s * sc + (w0 + w1 + w2 + w3);
        acc *= sc;
        acc += vA0 * w0; acc += vA1 * w1; acc += vA2 * w2; acc += vA3 * w3;
        m = mnew;
    }

    // ---- merge the 4 group states (lanes differ in bits 4,5) ----
    float mo = fmaxf(m, __shfl_xor(m, 16));
    mo = fmaxf(mo, __shfl_xor(mo, 32));
    const float f = __expf(m - mo);
    s *= f;
    acc *= f;
    s += __shfl_xor(s, 16);
    s += __shfl_xor(s, 32);
#pragma unroll
    for (int e = 0; e < 4; ++e) {
        float t = acc[e];
        t += __shfl_xor(t, 16);
        t += __shfl_xor(t, 32);
        acc[e] = t;
    }
    if (lg == 0) {
        const f32x4 res = acc / s;
        *(f32x4*)(out + (size_t)b * DD + d0) = res;
    }
}

extern "C" void kernel_launch(void* const* d_in, const int* in_sizes, int n_in,
                              void* d_out, int out_size, void* d_ws, size_t ws_size,
                              hipStream_t stream)
{
    const float* q   = (const float*)d_in[0];
    const float* k   = (const float*)d_in[1];
    const float* v   = (const float*)d_in[2];
    const int*  mask = (const int*)  d_in[3];
    const float* W1  = (const float*)d_in[4];
    const float* b1  = (const float*)d_in[5];
    const float* W2  = (const float*)d_in[6];
    const float* b2  = (const float*)d_in[7];
    const float* Wf  = (const float*)d_in[8];
    const float* bf  = (const float*)d_in[9];
    float* out = (float*)d_out;

    char* ws = (char*)d_ws;
    float*    wQh = (float*)   (ws + OFF_QH);
    _Float16* wF1 = (_Float16*)(ws + OFF_F1);
    _Float16* wF2 = (_Float16*)(ws + OFF_F2);

    prep_weights<<<16, 256, 0, stream>>>(W1, W2, wF1, wF2);
    prep_qh<<<(NB * NH1 + 255) / 256, 256, 0, stream>>>(q, W1, b1, wQh);
    attn_main<<<NB / 4, 256, 0, stream>>>(q, k, v, mask, Wf, b2, bf, wQh, wF1, wF2, out);
}

// Round 10
// 159.743 us; speedup vs baseline: 1.7504x; 1.7504x over previous
//
#include <hip/hip_runtime.h>
#include <cstddef>
#include <cmath>

#define NB  4096
#define TT  200
#define DD  64
#define NH1 80
#define NH2 40
#define NTILE 13
#define TPAD 208

typedef _Float16 half8 __attribute__((ext_vector_type(8)));
typedef float    f32x4 __attribute__((ext_vector_type(4)));

// ---- workspace layout (bytes) ----
static const size_t OFF_QH = 0;                                  // [4096][80] f32
static const size_t OFF_F1 = (size_t)NB * NH1 * 4;               // 20480 B
static const size_t OFF_F2 = OFF_F1 + (size_t)5 * 4 * 64 * 8 * 2;// 9216 B
static const size_t OFF_LG = OFF_F2 + (size_t)3 * 3 * 64 * 8 * 2;// [4096][208] f32

__global__ void prep_weights(const float* __restrict__ W1, const float* __restrict__ W2,
                             _Float16* __restrict__ wF1, _Float16* __restrict__ wF2)
{
    const int tid = blockIdx.x * blockDim.x + threadIdx.x;
    const int stride = blockDim.x * gridDim.x;
    for (int i = tid; i < 5 * 4 * 64 * 8; i += stride) {
        const int j = i & 7, l = (i >> 3) & 63, s = (i >> 9) & 3, n = i >> 11;
        const int h  = n * 16 + (l & 15);
        const int kk = s * 32 + (l >> 4) * 8 + j;
        const float w = (kk < 64) ? (W1[(64 + kk) * NH1 + h] - W1[(128 + kk) * NH1 + h])
                                  :  W1[(128 + kk) * NH1 + h];
        wF1[i] = (_Float16)w;
    }
    for (int i = tid; i < 3 * 3 * 64 * 8; i += stride) {
        const int j = i & 7, l = (i >> 3) & 63;
        const int s = (i >> 9) % 3, n = i / 1536;
        const int kk = s * 32 + (l >> 4) * 8 + j;
        const int n2 = n * 16 + (l & 15);
        const float w = (kk < NH1 && n2 < NH2) ? W2[kk * NH2 + n2] : 0.f;
        wF2[i] = (_Float16)w;
    }
}

__global__ void prep_qh(const float* __restrict__ q, const float* __restrict__ W1,
                        const float* __restrict__ b1, float* __restrict__ wQh)
{
    const int idx = blockIdx.x * blockDim.x + threadIdx.x;
    if (idx >= NB * NH1) return;
    const int b = idx / NH1;
    const int h = idx - b * NH1;
    const float* qb = q + (size_t)b * DD;
    float acc = b1[h];
#pragma unroll 8
    for (int d = 0; d < DD; ++d)
        acc += qb[d] * (W1[d * NH1 + h] + W1[(128 + d) * NH1 + h]);
    wQh[idx] = acc;
}

// ---------- Phase A: one wave per (b, tile) -> masked logits[4096][208] ----------
__global__ __launch_bounds__(256, 3)
void logits_kern(const float* __restrict__ q, const float* __restrict__ k,
                 const int* __restrict__ mask,
                 const float* __restrict__ Wf, const float* __restrict__ b2g,
                 const float* __restrict__ bf,
                 const float* __restrict__ wQh, const _Float16* __restrict__ wF1,
                 const _Float16* __restrict__ wF2, float* __restrict__ lgt)
{
    __shared__ __align__(16) _Float16 sWF1[5 * 4 * 64 * 8];   // 20480 B
    __shared__ __align__(16) _Float16 sWF2[3 * 3 * 64 * 8];   //  9216 B
    __shared__ __align__(16) char sH1[4 * 3072];              // per-wave h1

    const int tid  = threadIdx.x;
    const int wid  = tid >> 6;
    const int lane = tid & 63;
    const int lr   = lane & 15;
    const int lg   = lane >> 4;
    const int gt   = blockIdx.x * 4 + wid;     // global tile id
    const int b    = gt / NTILE;
    const int mt   = gt - b * NTILE;
    const float bfv = bf[0];

    // stage weight fragments into LDS (block-shared)
    {
        f32x4* dst1 = (f32x4*)sWF1;
        const f32x4* src1 = (const f32x4*)wF1;
        for (int i = tid; i < 1280; i += 256) dst1[i] = src1[i];
        f32x4* dst2 = (f32x4*)sWF2;
        const f32x4* src2 = (const f32x4*)wF2;
        for (int i = tid; i < 576; i += 256) dst2[i] = src2[i];
    }

    // per-lane slices of qh / Wf / b2
    float qhr[5];
#pragma unroll
    for (int n = 0; n < 5; ++n) qhr[n] = wQh[(size_t)b * NH1 + n * 16 + lr];
    float wfr[3], bbr[3];
#pragma unroll
    for (int n = 0; n < 3; ++n) {
        const int hc = n * 16 + lr;
        wfr[n] = (hc < NH2) ? Wf[hc]  : 0.f;
        bbr[n] = (hc < NH2) ? b2g[hc] : 0.f;
    }

    // q in packed fp16
    half8 qh0, qh1;
    {
        const float* qb = q + (size_t)b * DD;
#pragma unroll
        for (int j = 0; j < 8; ++j) qh0[j] = (_Float16)qb[lg * 8 + j];
#pragma unroll
        for (int j = 0; j < 8; ++j) qh1[j] = (_Float16)qb[32 + lg * 8 + j];
    }

    // zero-pad my wave's h1 cols 80..95 (slots 10,11), swizzled
    char* myH1 = sH1 + wid * 3072;
    if (lane < 32) {
        const int row = lane >> 1;
        const int slotL = 10 + (lane & 1);
        const f32x4 z4 = {};
        *(f32x4*)(myH1 + row * 192 + ((slotL ^ (row & 3)) << 4)) = z4;
    }

    __syncthreads();   // sWF1 / sWF2 ready

    const half8* sF1v = (const half8*)sWF1;
    const half8* sF2v = (const half8*)sWF2;

    // ---- k tile ----
    const int t = min(mt * 16 + lr, TT - 1);   // clamp; pad rows overwritten by -inf below
    const float* krow = k + ((size_t)b * TT + t) * DD;
    const f32x4 kc0 = *(const f32x4*)(krow + lg * 8);
    const f32x4 kc1 = *(const f32x4*)(krow + lg * 8 + 4);
    const f32x4 kc2 = *(const f32x4*)(krow + 32 + lg * 8);
    const f32x4 kc3 = *(const f32x4*)(krow + 32 + lg * 8 + 4);

    half8 af0, af1;
#pragma unroll
    for (int j = 0; j < 4; ++j) {
        af0[j] = (_Float16)kc0[j];  af0[j + 4] = (_Float16)kc1[j];
        af1[j] = (_Float16)kc2[j];  af1[j + 4] = (_Float16)kc3[j];
    }
    const half8 af2 = qh0 * af0;
    const half8 af3 = qh1 * af1;

    // ---- layer 1 MFMA, qh in C-init, relu -> per-wave LDS ----
#pragma unroll
    for (int n = 0; n < 5; ++n) {
        f32x4 a = { qhr[n], qhr[n], qhr[n], qhr[n] };
        a = __builtin_amdgcn_mfma_f32_16x16x32_f16(af0, sF1v[(n * 4 + 0) * 64 + lane], a, 0, 0, 0);
        a = __builtin_amdgcn_mfma_f32_16x16x32_f16(af1, sF1v[(n * 4 + 1) * 64 + lane], a, 0, 0, 0);
        a = __builtin_amdgcn_mfma_f32_16x16x32_f16(af2, sF1v[(n * 4 + 2) * 64 + lane], a, 0, 0, 0);
        a = __builtin_amdgcn_mfma_f32_16x16x32_f16(af3, sF1v[(n * 4 + 3) * 64 + lane], a, 0, 0, 0);
        const int slot   = (n * 16 + lr) >> 3;
        const int within = ((n * 16 + lr) & 7) * 2;
#pragma unroll
        for (int j = 0; j < 4; ++j) {
            const int r = lg * 4 + j;
            *(_Float16*)(myH1 + r * 192 + ((slot ^ (r & 3)) << 4) + within) = (_Float16)fmaxf(a[j], 0.f);
        }
    }

    // ---- layer 2 ----
    const half8 a2_0 = *(const half8*)(myH1 + lr * 192 + (((0 + lg) ^ (lr & 3)) << 4));
    const half8 a2_1 = *(const half8*)(myH1 + lr * 192 + (((4 + lg) ^ (lr & 3)) << 4));
    const half8 a2_2 = *(const half8*)(myH1 + lr * 192 + (((8 + lg) ^ (lr & 3)) << 4));

    float p0 = 0.f, p1 = 0.f, p2 = 0.f, p3 = 0.f;
#pragma unroll
    for (int n = 0; n < 3; ++n) {
        f32x4 c2 = { bbr[n], bbr[n], bbr[n], bbr[n] };
        c2 = __builtin_amdgcn_mfma_f32_16x16x32_f16(a2_0, sF2v[(n * 3 + 0) * 64 + lane], c2, 0, 0, 0);
        c2 = __builtin_amdgcn_mfma_f32_16x16x32_f16(a2_1, sF2v[(n * 3 + 1) * 64 + lane], c2, 0, 0, 0);
        c2 = __builtin_amdgcn_mfma_f32_16x16x32_f16(a2_2, sF2v[(n * 3 + 2) * 64 + lane], c2, 0, 0, 0);
        p0 = fmaf(fmaxf(c2[0], 0.f), wfr[n], p0);
        p1 = fmaf(fmaxf(c2[1], 0.f), wfr[n], p1);
        p2 = fmaf(fmaxf(c2[2], 0.f), wfr[n], p2);
        p3 = fmaf(fmaxf(c2[3], 0.f), wfr[n], p3);
    }
#pragma unroll
    for (int off = 1; off < 16; off <<= 1) {
        p0 += __shfl_xor(p0, off);
        p1 += __shfl_xor(p1, off);
        p2 += __shfl_xor(p2, off);
        p3 += __shfl_xor(p3, off);
    }

    // ---- masked logit store (lanes lr==0 hold the row sums) ----
    if (lr == 0) {
        const int tr = mt * 16 + lg * 4;
        float pj0 = p0, pj1 = p1, pj2 = p2, pj3 = p3;
        f32x4 o;
        {
            const int row = tr + 0;
            const float bias = (row < TT) ? (mask[(size_t)b * TT + row] ? 3.0e38f : -4294967295.0f) : -INFINITY;
            o[0] = fminf(pj0 + bfv, bias);
        }
        {
            const int row = tr + 1;
            const float bias = (row < TT) ? (mask[(size_t)b * TT + row] ? 3.0e38f : -4294967295.0f) : -INFINITY;
            o[1] = fminf(pj1 + bfv, bias);
        }
        {
            const int row = tr + 2;
            const float bias = (row < TT) ? (mask[(size_t)b * TT + row] ? 3.0e38f : -4294967295.0f) : -INFINITY;
            o[2] = fminf(pj2 + bfv, bias);
        }
        {
            const int row = tr + 3;
            const float bias = (row < TT) ? (mask[(size_t)b * TT + row] ? 3.0e38f : -4294967295.0f) : -INFINITY;
            o[3] = fminf(pj3 + bfv, bias);
        }
        *(f32x4*)(lgt + (size_t)b * TPAD + tr) = o;
    }
}

// ---------- Phase B: one wave per b -> softmax + weighted v sum ----------
__global__ __launch_bounds__(256, 4)
void attn_out_kern(const float* __restrict__ v, const float* __restrict__ lgt,
                   float* __restrict__ out)
{
    __shared__ float sW[4][TPAD];

    const int tid  = threadIdx.x;
    const int wid  = tid >> 6;
    const int lane = tid & 63;
    const int lr   = lane & 15;
    const int lg   = lane >> 4;
    const int b    = blockIdx.x * 4 + wid;
    const int d0   = lr * 4;

    // load logits (4 strided slots per lane; pads are -inf from phase A)
    float l0 = lgt[(size_t)b * TPAD + lane];
    float l1 = lgt[(size_t)b * TPAD + lane + 64];
    float l2 = lgt[(size_t)b * TPAD + lane + 128];
    const int i3 = lane + 192;
    float l3 = (i3 < TPAD) ? lgt[(size_t)b * TPAD + i3] : -INFINITY;

    // global max (butterfly over 64 lanes)
    float M = fmaxf(fmaxf(l0, l1), fmaxf(l2, l3));
#pragma unroll
    for (int off = 32; off > 0; off >>= 1) M = fmaxf(M, __shfl_xor(M, off));

    // exp + global sum
    const float e0 = __expf(l0 - M);
    const float e1 = __expf(l1 - M);
    const float e2 = __expf(l2 - M);
    const float e3 = (i3 < TPAD) ? __expf(l3 - M) : 0.f;
    float S = e0 + e1 + e2 + e3;
#pragma unroll
    for (int off = 32; off > 0; off >>= 1) S += __shfl_xor(S, off);

    // unnormalized weights to LDS (wave-private row)
    sW[wid][lane]       = e0;
    sW[wid][lane + 64]  = e1;
    sW[wid][lane + 128] = e2;
    if (i3 < TPAD) sW[wid][i3] = e3;

    // weighted v sum: 13 iterations of 16 rows (lg group handles 4 rows each)
    const float* vb = v + (size_t)b * (TT * DD);
    f32x4 acc = {};
#pragma unroll
    for (int mt = 0; mt < 13; ++mt) {
        const int tr = mt * 16 + lg * 4;
        const f32x4 w4 = *(const f32x4*)&sW[wid][tr];
        const f32x4 vA = *(const f32x4*)(vb + (size_t)min(tr + 0, TT - 1) * DD + d0);
        const f32x4 vB = *(const f32x4*)(vb + (size_t)min(tr + 1, TT - 1) * DD + d0);
        const f32x4 vC = *(const f32x4*)(vb + (size_t)min(tr + 2, TT - 1) * DD + d0);
        const f32x4 vD = *(const f32x4*)(vb + (size_t)min(tr + 3, TT - 1) * DD + d0);
        acc += vA * w4[0];
        acc += vB * w4[1];
        acc += vC * w4[2];
        acc += vD * w4[3];
    }

    // merge the 4 lg-groups (lanes differ in bits 4,5), normalize, store
#pragma unroll
    for (int e = 0; e < 4; ++e) {
        float t = acc[e];
        t += __shfl_xor(t, 16);
        t += __shfl_xor(t, 32);
        acc[e] = t;
    }
    if (lg == 0) {
        const f32x4 res = acc / S;
        *(f32x4*)(out + (size_t)b * DD + d0) = res;
    }
}

extern "C" void kernel_launch(void* const* d_in, const int* in_sizes, int n_in,
                              void* d_out, int out_size, void* d_ws, size_t ws_size,
                              hipStream_t stream)
{
    const float* q   = (const float*)d_in[0];
    const float* k   = (const float*)d_in[1];
    const float* v   = (const float*)d_in[2];
    const int*  mask = (const int*)  d_in[3];
    const float* W1  = (const float*)d_in[4];
    const float* b1  = (const float*)d_in[5];
    const float* W2  = (const float*)d_in[6];
    const float* b2  = (const float*)d_in[7];
    const float* Wf  = (const float*)d_in[8];
    const float* bf  = (const float*)d_in[9];
    float* out = (float*)d_out;

    char* ws = (char*)d_ws;
    float*    wQh = (float*)   (ws + OFF_QH);
    _Float16* wF1 = (_Float16*)(ws + OFF_F1);
    _Float16* wF2 = (_Float16*)(ws + OFF_F2);
    float*    lgt = (float*)   (ws + OFF_LG);

    prep_weights<<<16, 256, 0, stream>>>(W1, W2, wF1, wF2);
    prep_qh<<<(NB * NH1 + 255) / 256, 256, 0, stream>>>(q, W1, b1, wQh);
    logits_kern<<<NB * NTILE / 4, 256, 0, stream>>>(q, k, mask, Wf, b2, bf, wQh, wF1, wF2, lgt);
    attn_out_kern<<<NB / 4, 256, 0, stream>>>(v, lgt, out);
}